// Round 1
// baseline (212.976 us; speedup 1.0000x reference)
//
#include <hip/hip_runtime.h>
#include <hip/hip_bf16.h>

#define HD 768
#define SQ 256
#define NB 4
#define RR 7

__device__ __forceinline__ float fast_tanh(float x) {
  // tanh(x) = 1 - 2/(e^{2x}+1); stable for |x| large (inf -> 1, 0 -> -1)
  float e = __expf(2.0f * x);
  return 1.0f - 2.0f / (e + 1.0f);
}

__device__ __forceinline__ float pair_tanh(float a, float b) {
  // tanh(u+v) = (a+b)/(1+ab) with a=tanh u, b=tanh v  (exact identity)
  return (a + b) * __builtin_amdgcn_rcpf(fmaf(a, b, 1.0f));
}

// ---------------- Stage 1: ta/tb = tanh(X @ W^T + bias) ----------------
// X: [1024, 768], W: [768, 768] (rows = output features), out: [1024, 768]
__global__ __launch_bounds__(256) void stage1_kernel(
    const float* __restrict__ X,
    const float* __restrict__ Wsrc, const float* __restrict__ bsrc,
    const float* __restrict__ Wtgt, const float* __restrict__ btgt,
    float* __restrict__ ta, float* __restrict__ tb)
{
  constexpr int BM = 64, BN = 64, BK = 32;
  const float* W  = blockIdx.z ? Wtgt : Wsrc;
  const float* bv = blockIdx.z ? btgt : bsrc;
  float* outp     = blockIdx.z ? tb : ta;

  const int row0 = blockIdx.x * BM;
  const int col0 = blockIdx.y * BN;

  __shared__ float As[BK][BM + 4];  // k-major so fragment reads are b128
  __shared__ float Bs[BK][BN + 4];

  const int tid = threadIdx.x;
  const int tx = tid & 15, ty = tid >> 4;

  float acc[4][4] = {};

  for (int k0 = 0; k0 < HD; k0 += BK) {
    // stage 64x32 tiles of X and W (transpose into k-major LDS)
    #pragma unroll
    for (int j = 0; j < 2; ++j) {
      int idx = tid + 256 * j;       // 512 float4 total
      int r = idx >> 3;              // 8 float4 per row of 32 k
      int q = idx & 7;
      float4 va = *(const float4*)(X + (size_t)(row0 + r) * HD + k0 + q * 4);
      As[q*4+0][r] = va.x; As[q*4+1][r] = va.y;
      As[q*4+2][r] = va.z; As[q*4+3][r] = va.w;
      float4 vb = *(const float4*)(W + (size_t)(col0 + r) * HD + k0 + q * 4);
      Bs[q*4+0][r] = vb.x; Bs[q*4+1][r] = vb.y;
      Bs[q*4+2][r] = vb.z; Bs[q*4+3][r] = vb.w;
    }
    __syncthreads();

    #pragma unroll
    for (int k = 0; k < BK; ++k) {
      float4 a = *(const float4*)&As[k][ty * 4];
      float4 b = *(const float4*)&Bs[k][tx * 4];
      float av[4] = {a.x, a.y, a.z, a.w};
      float bw[4] = {b.x, b.y, b.z, b.w};
      #pragma unroll
      for (int i = 0; i < 4; ++i)
        #pragma unroll
        for (int j = 0; j < 4; ++j)
          acc[i][j] = fmaf(av[i], bw[j], acc[i][j]);
    }
    __syncthreads();
  }

  #pragma unroll
  for (int i = 0; i < 4; ++i) {
    int row = row0 + ty * 4 + i;
    int col = col0 + tx * 4;
    float4 o;
    o.x = fast_tanh(acc[i][0] + bv[col + 0]);
    o.y = fast_tanh(acc[i][1] + bv[col + 1]);
    o.z = fast_tanh(acc[i][2] + bv[col + 2]);
    o.w = fast_tanh(acc[i][3] + bv[col + 3]);
    *(float4*)(outp + (size_t)row * HD + col) = o;
  }
}

// ---------------- Stage 2: out[b,s,t,r] = sum_h w[r,h]*pair_tanh ----------------
__global__ __launch_bounds__(256) void stage2_kernel(
    const float* __restrict__ ta, const float* __restrict__ tb,
    const float* __restrict__ Wout, float* __restrict__ out)
{
  constexpr int HC = 128;   // h chunk
  constexpr int LD = 132;   // LDS row stride (floats): breaks 512B bank aliasing

  const int b  = blockIdx.z;
  const int s0 = blockIdx.y * 32;
  const int t0 = blockIdx.x * 32;

  __shared__ float sa[32][LD];
  __shared__ float sb[32][LD];

  const int tid = threadIdx.x;
  const int tx = tid & 15, ty = tid >> 4;

  float acc[4][RR] = {};  // pairs: (ty,tx),(ty,tx+16),(ty+16,tx),(ty+16,tx+16)

  const float* taB = ta + ((size_t)b * SQ + s0) * HD;
  const float* tbB = tb + ((size_t)b * SQ + t0) * HD;

  for (int h0 = 0; h0 < HD; h0 += HC) {
    #pragma unroll
    for (int j = 0; j < 4; ++j) {   // 32*128 floats = 1024 float4 / 256 thr
      int idx = tid + 256 * j;
      int r = idx >> 5;             // 32 float4 per row
      int q = idx & 31;
      *(float4*)&sa[r][q * 4] = *(const float4*)(taB + (size_t)r * HD + h0 + q * 4);
      *(float4*)&sb[r][q * 4] = *(const float4*)(tbB + (size_t)r * HD + h0 + q * 4);
    }
    __syncthreads();

    #pragma unroll 2
    for (int e4 = 0; e4 < HC; e4 += 4) {
      float4 A0 = *(const float4*)&sa[ty     ][e4];
      float4 A1 = *(const float4*)&sa[ty + 16][e4];
      float4 B0 = *(const float4*)&sb[tx     ][e4];
      float4 B1 = *(const float4*)&sb[tx + 16][e4];
      float a0[4] = {A0.x, A0.y, A0.z, A0.w};
      float a1[4] = {A1.x, A1.y, A1.z, A1.w};
      float b0[4] = {B0.x, B0.y, B0.z, B0.w};
      float b1[4] = {B1.x, B1.y, B1.z, B1.w};
      #pragma unroll
      for (int e = 0; e < 4; ++e) {
        float w[RR];
        #pragma unroll
        for (int r = 0; r < RR; ++r)
          w[r] = Wout[r * HD + h0 + e4 + e];  // wave-uniform -> s_load
        float f00 = pair_tanh(a0[e], b0[e]);
        float f01 = pair_tanh(a0[e], b1[e]);
        float f10 = pair_tanh(a1[e], b0[e]);
        float f11 = pair_tanh(a1[e], b1[e]);
        #pragma unroll
        for (int r = 0; r < RR; ++r) {
          acc[0][r] = fmaf(f00, w[r], acc[0][r]);
          acc[1][r] = fmaf(f01, w[r], acc[1][r]);
          acc[2][r] = fmaf(f10, w[r], acc[2][r]);
          acc[3][r] = fmaf(f11, w[r], acc[3][r]);
        }
      }
    }
    __syncthreads();
  }

  #pragma unroll
  for (int i = 0; i < 2; ++i) {
    int s = s0 + ty + 16 * i;
    #pragma unroll
    for (int j = 0; j < 2; ++j) {
      int t = t0 + tx + 16 * j;
      float* o = out + (((size_t)b * SQ + s) * SQ + t) * RR;
      #pragma unroll
      for (int r = 0; r < RR; ++r) o[r] = acc[i * 2 + j][r];
    }
  }
}

extern "C" void kernel_launch(void* const* d_in, const int* in_sizes, int n_in,
                              void* d_out, int out_size, void* d_ws, size_t ws_size,
                              hipStream_t stream) {
  (void)in_sizes; (void)n_in; (void)out_size; (void)ws_size;
  const float* X    = (const float*)d_in[0];
  const float* Wsrc = (const float*)d_in[1];
  const float* bsrc = (const float*)d_in[2];
  const float* Wtgt = (const float*)d_in[3];
  const float* btgt = (const float*)d_in[4];
  const float* Wout = (const float*)d_in[5];
  float* out = (float*)d_out;

  float* ta = (float*)d_ws;                      // [4*256, 768]
  float* tb = ta + (size_t)NB * SQ * HD;         // [4*256, 768]

  stage1_kernel<<<dim3(16, 12, 2), 256, 0, stream>>>(X, Wsrc, bsrc, Wtgt, btgt, ta, tb);
  stage2_kernel<<<dim3(SQ / 32, SQ / 32, NB), 256, 0, stream>>>(ta, tb, Wout, out);
}

// Round 3
// 152.742 us; speedup vs baseline: 1.3944x; 1.3944x over previous
//
#include <hip/hip_runtime.h>
#include <hip/hip_bf16.h>

#define HD 768
#define SQ 256
#define NB 4
#define RR 7

typedef short bf16x8 __attribute__((ext_vector_type(8)));
typedef float f32x4  __attribute__((ext_vector_type(4)));

__device__ __forceinline__ float fast_tanh(float x) {
  // tanh(x) = 1 - 2/(e^{2x}+1); stable for large |x|
  float e = __expf(2.0f * x);
  return 1.0f - 2.0f / (e + 1.0f);
}

__device__ __forceinline__ float pair_tanh(float a, float b) {
  // tanh(u+v) = (a+b)/(1+ab) with a=tanh u, b=tanh v  (exact identity)
  return (a + b) * __builtin_amdgcn_rcpf(fmaf(a, b, 1.0f));
}

__device__ __forceinline__ short f2bf(float x) {
  // round-to-nearest-even f32 -> bf16 (inputs finite)
  uint32_t u = __builtin_bit_cast(uint32_t, x);
  u += 0x7FFFu + ((u >> 16) & 1u);
  return (short)(u >> 16);
}

__device__ __forceinline__ bf16x8 pack8(float4 a, float4 b) {
  bf16x8 r;
  r[0] = f2bf(a.x); r[1] = f2bf(a.y); r[2] = f2bf(a.z); r[3] = f2bf(a.w);
  r[4] = f2bf(b.x); r[5] = f2bf(b.y); r[6] = f2bf(b.z); r[7] = f2bf(b.w);
  return r;
}

// ---------------- Stage 1 (MFMA bf16): ta/tb = tanh(X @ W^T + bias) ----------------
// X: [1024,768] f32, W: [768,768] f32 (row = output feature), out: [1024,768] f32
__global__ __launch_bounds__(256) void stage1_mfma(
    const float* __restrict__ X,
    const float* __restrict__ Wsrc, const float* __restrict__ bsrc,
    const float* __restrict__ Wtgt, const float* __restrict__ btgt,
    float* __restrict__ ta, float* __restrict__ tb)
{
  constexpr int BM = 64, BN = 64, BK = 64;
  const float* W  = blockIdx.z ? Wtgt : Wsrc;
  const float* bv = blockIdx.z ? btgt : bsrc;
  float* outp     = blockIdx.z ? tb : ta;

  const int row0 = blockIdx.x * BM;
  const int col0 = blockIdx.y * BN;

  // bf16 tiles, row-major [64 rows][64 k]; 8 granules (16B) per row,
  // XOR-swizzled: granule' = granule ^ (row & 7)  -> conflict-free b128 r/w
  __shared__ short As[BM * BK];
  __shared__ short Bs[BN * BK];

  const int tid  = threadIdx.x;
  const int wave = tid >> 6;
  const int lane = tid & 63;
  const int wm = (wave >> 1) * 32;   // wave's 32x32 quadrant
  const int wn = (wave & 1) * 32;

  f32x4 acc[2][2] = {};

  // staging: 4 threads per row, each converts 16 f32 -> two 16B granules
  const int sr = tid >> 2;       // 0..63
  const int sq = tid & 3;        // 0..3 -> k quarter (16 floats)

  for (int k0 = 0; k0 < HD; k0 += BK) {
    const float* xa = X + (size_t)(row0 + sr) * HD + k0 + sq * 16;
    const float* xw = W + (size_t)(col0 + sr) * HD + k0 + sq * 16;
    float4 a0 = *(const float4*)(xa + 0);
    float4 a1 = *(const float4*)(xa + 4);
    float4 a2 = *(const float4*)(xa + 8);
    float4 a3 = *(const float4*)(xa + 12);
    float4 w0 = *(const float4*)(xw + 0);
    float4 w1 = *(const float4*)(xw + 4);
    float4 w2 = *(const float4*)(xw + 8);
    float4 w3 = *(const float4*)(xw + 12);
    __syncthreads();   // protect previous iteration's reads
    *(bf16x8*)&As[sr * BK + (((sq * 2 + 0) ^ (sr & 7)) * 8)] = pack8(a0, a1);
    *(bf16x8*)&As[sr * BK + (((sq * 2 + 1) ^ (sr & 7)) * 8)] = pack8(a2, a3);
    *(bf16x8*)&Bs[sr * BK + (((sq * 2 + 0) ^ (sr & 7)) * 8)] = pack8(w0, w1);
    *(bf16x8*)&Bs[sr * BK + (((sq * 2 + 1) ^ (sr & 7)) * 8)] = pack8(w2, w3);
    __syncthreads();

    #pragma unroll
    for (int kkb = 0; kkb < 2; ++kkb) {   // two K=32 chunks
      bf16x8 af[2], bw[2];
      #pragma unroll
      for (int i = 0; i < 2; ++i) {
        int ar = wm + i * 16 + (lane & 15);
        af[i] = *(const bf16x8*)&As[ar * BK + (((kkb * 4 + (lane >> 4)) ^ (lane & 7)) * 8)];
        int br = wn + i * 16 + (lane & 15);
        bw[i] = *(const bf16x8*)&Bs[br * BK + (((kkb * 4 + (lane >> 4)) ^ (lane & 7)) * 8)];
      }
      #pragma unroll
      for (int i = 0; i < 2; ++i)
        #pragma unroll
        for (int j = 0; j < 2; ++j)
          acc[i][j] = __builtin_amdgcn_mfma_f32_16x16x32_bf16(af[i], bw[j], acc[i][j], 0, 0, 0);
    }
  }

  // epilogue: D row=(lane>>4)*4+reg (M dim), col=lane&15 (N dim)
  #pragma unroll
  for (int j = 0; j < 2; ++j) {
    int n = col0 + wn + j * 16 + (lane & 15);
    float bb = bv[n];
    #pragma unroll
    for (int i = 0; i < 2; ++i) {
      #pragma unroll
      for (int r = 0; r < 4; ++r) {
        int m = row0 + wm + i * 16 + (lane >> 4) * 4 + r;
        outp[(size_t)m * HD + n] = fast_tanh(acc[i][j][r] + bb);
      }
    }
  }
}

// ---------------- Stage 2: out[b,s,t,r] = sum_h w[r,h]*pair_tanh ----------------
__global__ __launch_bounds__(256) void stage2_kernel(
    const float* __restrict__ ta, const float* __restrict__ tb,
    const float* __restrict__ Wout, float* __restrict__ out)
{
  constexpr int HC = 128;   // h chunk
  constexpr int LD = 132;   // LDS row stride (floats)

  const int b  = blockIdx.z;
  const int s0 = blockIdx.y * 16;
  const int t0 = blockIdx.x * 16;

  __shared__ float sa[16][LD];
  __shared__ float sb[16][LD];

  const int tid = threadIdx.x;
  const int tx = tid & 15, ty = tid >> 4;

  float acc[RR] = {};

  const float* taB = ta + ((size_t)b * SQ + s0) * HD;
  const float* tbB = tb + ((size_t)b * SQ + t0) * HD;

  for (int h0 = 0; h0 < HD; h0 += HC) {
    #pragma unroll
    for (int j = 0; j < 2; ++j) {   // 16*128 floats x2 = 1024 float4 / 256 thr
      int idx = tid + 256 * j;      // 0..511
      int r = idx >> 5;             // 32 float4 per row
      int q = idx & 31;
      *(float4*)&sa[r][q * 4] = *(const float4*)(taB + (size_t)r * HD + h0 + q * 4);
      *(float4*)&sb[r][q * 4] = *(const float4*)(tbB + (size_t)r * HD + h0 + q * 4);
    }
    __syncthreads();

    #pragma unroll 2
    for (int e4 = 0; e4 < HC; e4 += 4) {
      float4 A = *(const float4*)&sa[ty][e4];
      float4 B = *(const float4*)&sb[tx][e4];
      float av[4] = {A.x, A.y, A.z, A.w};
      float bv[4] = {B.x, B.y, B.z, B.w};
      #pragma unroll
      for (int e = 0; e < 4; ++e) {
        float w[RR];
        #pragma unroll
        for (int r = 0; r < RR; ++r)
          w[r] = Wout[r * HD + h0 + e4 + e];   // wave-uniform -> s_load
        float f = pair_tanh(av[e], bv[e]);
        #pragma unroll
        for (int r = 0; r < RR; ++r)
          acc[r] = fmaf(f, w[r], acc[r]);
      }
    }
    __syncthreads();
  }

  float* o = out + (((size_t)b * SQ + (s0 + ty)) * SQ + (t0 + tx)) * RR;
  #pragma unroll
  for (int r = 0; r < RR; ++r) o[r] = acc[r];
}

extern "C" void kernel_launch(void* const* d_in, const int* in_sizes, int n_in,
                              void* d_out, int out_size, void* d_ws, size_t ws_size,
                              hipStream_t stream) {
  (void)in_sizes; (void)n_in; (void)out_size; (void)ws_size;
  const float* X    = (const float*)d_in[0];
  const float* Wsrc = (const float*)d_in[1];
  const float* bsrc = (const float*)d_in[2];
  const float* Wtgt = (const float*)d_in[3];
  const float* btgt = (const float*)d_in[4];
  const float* Wout = (const float*)d_in[5];
  float* out = (float*)d_out;

  float* ta = (float*)d_ws;                      // [1024, 768]
  float* tb = ta + (size_t)NB * SQ * HD;         // [1024, 768]

  stage1_mfma<<<dim3(16, 12, 2), 256, 0, stream>>>(X, Wsrc, bsrc, Wtgt, btgt, ta, tb);
  stage2_kernel<<<dim3(SQ / 16, SQ / 16, NB), 256, 0, stream>>>(ta, tb, Wout, out);
}

// Round 4
// 117.393 us; speedup vs baseline: 1.8142x; 1.3011x over previous
//
#include <hip/hip_runtime.h>
#include <hip/hip_bf16.h>

#define HD 768
#define SQ 256
#define NB 4
#define RR 7

typedef short bf16x8 __attribute__((ext_vector_type(8)));
typedef float f32x4  __attribute__((ext_vector_type(4)));

__device__ __forceinline__ float fast_tanh(float x) {
  // tanh(x) = 1 - 2/(e^{2x}+1); stable for large |x|
  float e = __expf(2.0f * x);
  return 1.0f - 2.0f / (e + 1.0f);
}

__device__ __forceinline__ float pair_tanh(float a, float b) {
  // tanh(u+v) = (a+b)/(1+ab) with a=tanh u, b=tanh v (exact identity)
  return (a + b) * __builtin_amdgcn_rcpf(fmaf(a, b, 1.0f));
}

__device__ __forceinline__ short f2bf(float x) {
  // compiler lowers scalar casts to v_cvt_pk_bf16_f32 pairs (m240)
  return (short)__builtin_bit_cast(unsigned short, __float2bfloat16(x));
}

__device__ __forceinline__ void gl_lds16(const void* g, void* l) {
  // async 16B/lane global->LDS; LDS dest = wave-uniform base + lane*16
  __builtin_amdgcn_global_load_lds(
      (const __attribute__((address_space(1))) void*)g,
      (__attribute__((address_space(3))) void*)l, 16, 0, 0);
}

// ---------------- convert: f32 -> bf16 for X, Wsrc, Wtgt ----------------
__global__ __launch_bounds__(256) void cvt_kernel(
    const float* __restrict__ X, const float* __restrict__ Ws,
    const float* __restrict__ Wt,
    short* __restrict__ Xb, short* __restrict__ Wsb, short* __restrict__ Wtb)
{
  const int NX = NB * SQ * HD / 8;   // 98304 octets
  const int NW = HD * HD / 8;        // 73728 octets
  int i = blockIdx.x * 256 + threadIdx.x;
  const float* src; short* dst;
  if (i < NX)               { src = X;  dst = Xb; }
  else if (i < NX + NW)     { src = Ws; dst = Wsb; i -= NX; }
  else if (i < NX + 2 * NW) { src = Wt; dst = Wtb; i -= NX + NW; }
  else return;
  float4 a = *(const float4*)(src + (size_t)i * 8);
  float4 b = *(const float4*)(src + (size_t)i * 8 + 4);
  bf16x8 r;
  r[0] = f2bf(a.x); r[1] = f2bf(a.y); r[2] = f2bf(a.z); r[3] = f2bf(a.w);
  r[4] = f2bf(b.x); r[5] = f2bf(b.y); r[6] = f2bf(b.z); r[7] = f2bf(b.w);
  *(bf16x8*)(dst + (size_t)i * 8) = r;
}

// -------- Stage 1 fast: ta/tb = tanh(Xb @ Wb^T + bias), global_load_lds --------
__global__ __launch_bounds__(256) void stage1_lds(
    const short* __restrict__ Xb,
    const short* __restrict__ Wsb, const float* __restrict__ bsrc,
    const short* __restrict__ Wtb, const float* __restrict__ btgt,
    float* __restrict__ ta, float* __restrict__ tb)
{
  constexpr int BK = 64;
  const short* W  = blockIdx.z ? Wtb : Wsb;
  const float* bv = blockIdx.z ? btgt : bsrc;
  float* outp     = blockIdx.z ? tb : ta;
  const int row0 = blockIdx.x * 64, col0 = blockIdx.y * 64;

  // linear LDS [64 rows][8 granules of 16B]; content granule(r,g) = global (r, g^(r&7))
  __shared__ short As[64 * BK];
  __shared__ short Bs[64 * BK];

  const int tid = threadIdx.x, wave = tid >> 6, lane = tid & 63;
  const int wm = (wave >> 1) * 32, wn = (wave & 1) * 32;

  f32x4 acc[2][2] = {};

  const int G0 = wave * 64 + lane;          // issue-0 granule
  const int r0 = G0 >> 3, g0 = G0 & 7;
  const int G1 = G0 + 256;                  // issue-1 granule
  const int r1 = G1 >> 3, g1 = G1 & 7;

  for (int k0 = 0; k0 < HD; k0 += BK) {
    __syncthreads();   // prev reads done before overwrite
    gl_lds16(Xb + (size_t)(row0 + r0) * HD + k0 + ((g0 ^ (r0 & 7)) * 8),
             As + (size_t)(wave * 64) * 8);
    gl_lds16(Xb + (size_t)(row0 + r1) * HD + k0 + ((g1 ^ (r1 & 7)) * 8),
             As + (size_t)(256 + wave * 64) * 8);
    gl_lds16(W + (size_t)(col0 + r0) * HD + k0 + ((g0 ^ (r0 & 7)) * 8),
             Bs + (size_t)(wave * 64) * 8);
    gl_lds16(W + (size_t)(col0 + r1) * HD + k0 + ((g1 ^ (r1 & 7)) * 8),
             Bs + (size_t)(256 + wave * 64) * 8);
    __syncthreads();   // drains vmcnt -> tiles ready

    #pragma unroll
    for (int kkb = 0; kkb < 2; ++kkb) {
      bf16x8 af[2], bw[2];
      const int q = kkb * 4 + (lane >> 4);
      #pragma unroll
      for (int i = 0; i < 2; ++i) {
        int ar = wm + i * 16 + (lane & 15);
        af[i] = *(const bf16x8*)&As[ar * BK + ((q ^ (ar & 7)) * 8)];
        int br = wn + i * 16 + (lane & 15);
        bw[i] = *(const bf16x8*)&Bs[br * BK + ((q ^ (br & 7)) * 8)];
      }
      #pragma unroll
      for (int i = 0; i < 2; ++i)
        #pragma unroll
        for (int j = 0; j < 2; ++j)
          acc[i][j] = __builtin_amdgcn_mfma_f32_16x16x32_bf16(af[i], bw[j], acc[i][j], 0, 0, 0);
    }
  }

  #pragma unroll
  for (int j = 0; j < 2; ++j) {
    int n = col0 + wn + j * 16 + (lane & 15);
    float bb = bv[n];
    #pragma unroll
    for (int i = 0; i < 2; ++i)
      #pragma unroll
      for (int r = 0; r < 4; ++r) {
        int m = row0 + wm + i * 16 + (lane >> 4) * 4 + r;
        outp[(size_t)m * HD + n] = fast_tanh(acc[i][j][r] + bb);
      }
  }
}

// -------- Stage 1 fallback (in-kernel convert; used if ws too small) --------
__global__ __launch_bounds__(256) void stage1_mfma(
    const float* __restrict__ X,
    const float* __restrict__ Wsrc, const float* __restrict__ bsrc,
    const float* __restrict__ Wtgt, const float* __restrict__ btgt,
    float* __restrict__ ta, float* __restrict__ tb)
{
  constexpr int BK = 64;
  const float* W  = blockIdx.z ? Wtgt : Wsrc;
  const float* bv = blockIdx.z ? btgt : bsrc;
  float* outp     = blockIdx.z ? tb : ta;
  const int row0 = blockIdx.x * 64, col0 = blockIdx.y * 64;

  __shared__ short As[64 * BK];
  __shared__ short Bs[64 * BK];

  const int tid  = threadIdx.x;
  const int wave = tid >> 6, lane = tid & 63;
  const int wm = (wave >> 1) * 32, wn = (wave & 1) * 32;
  f32x4 acc[2][2] = {};
  const int sr = tid >> 2, sq = tid & 3;

  for (int k0 = 0; k0 < HD; k0 += BK) {
    const float* xa = X + (size_t)(row0 + sr) * HD + k0 + sq * 16;
    const float* xw = W + (size_t)(col0 + sr) * HD + k0 + sq * 16;
    float4 a0 = *(const float4*)(xa + 0), a1 = *(const float4*)(xa + 4);
    float4 a2 = *(const float4*)(xa + 8), a3 = *(const float4*)(xa + 12);
    float4 w0 = *(const float4*)(xw + 0), w1 = *(const float4*)(xw + 4);
    float4 w2 = *(const float4*)(xw + 8), w3 = *(const float4*)(xw + 12);
    __syncthreads();
    bf16x8 p;
    p[0]=f2bf(a0.x);p[1]=f2bf(a0.y);p[2]=f2bf(a0.z);p[3]=f2bf(a0.w);
    p[4]=f2bf(a1.x);p[5]=f2bf(a1.y);p[6]=f2bf(a1.z);p[7]=f2bf(a1.w);
    *(bf16x8*)&As[sr * BK + (((sq * 2 + 0) ^ (sr & 7)) * 8)] = p;
    p[0]=f2bf(a2.x);p[1]=f2bf(a2.y);p[2]=f2bf(a2.z);p[3]=f2bf(a2.w);
    p[4]=f2bf(a3.x);p[5]=f2bf(a3.y);p[6]=f2bf(a3.z);p[7]=f2bf(a3.w);
    *(bf16x8*)&As[sr * BK + (((sq * 2 + 1) ^ (sr & 7)) * 8)] = p;
    p[0]=f2bf(w0.x);p[1]=f2bf(w0.y);p[2]=f2bf(w0.z);p[3]=f2bf(w0.w);
    p[4]=f2bf(w1.x);p[5]=f2bf(w1.y);p[6]=f2bf(w1.z);p[7]=f2bf(w1.w);
    *(bf16x8*)&Bs[sr * BK + (((sq * 2 + 0) ^ (sr & 7)) * 8)] = p;
    p[0]=f2bf(w2.x);p[1]=f2bf(w2.y);p[2]=f2bf(w2.z);p[3]=f2bf(w2.w);
    p[4]=f2bf(w3.x);p[5]=f2bf(w3.y);p[6]=f2bf(w3.z);p[7]=f2bf(w3.w);
    *(bf16x8*)&Bs[sr * BK + (((sq * 2 + 1) ^ (sr & 7)) * 8)] = p;
    __syncthreads();

    #pragma unroll
    for (int kkb = 0; kkb < 2; ++kkb) {
      bf16x8 af[2], bw[2];
      const int q = kkb * 4 + (lane >> 4);
      #pragma unroll
      for (int i = 0; i < 2; ++i) {
        int ar = wm + i * 16 + (lane & 15);
        af[i] = *(const bf16x8*)&As[ar * BK + ((q ^ (ar & 7)) * 8)];
        int br = wn + i * 16 + (lane & 15);
        bw[i] = *(const bf16x8*)&Bs[br * BK + ((q ^ (br & 7)) * 8)];
      }
      #pragma unroll
      for (int i = 0; i < 2; ++i)
        #pragma unroll
        for (int j = 0; j < 2; ++j)
          acc[i][j] = __builtin_amdgcn_mfma_f32_16x16x32_bf16(af[i], bw[j], acc[i][j], 0, 0, 0);
    }
  }

  #pragma unroll
  for (int j = 0; j < 2; ++j) {
    int n = col0 + wn + j * 16 + (lane & 15);
    float bb = bv[n];
    #pragma unroll
    for (int i = 0; i < 2; ++i)
      #pragma unroll
      for (int r = 0; r < 4; ++r) {
        int m = row0 + wm + i * 16 + (lane >> 4) * 4 + r;
        outp[(size_t)m * HD + n] = fast_tanh(acc[i][j][r] + bb);
      }
  }
}

// ---- Stage 2: out[b,s,t,r] = sum_h Wout[r,h]*pair_tanh -> MFMA over (t x r) ----
// block: 16s x 16t tile, 4 waves = (s-half, K-half); LDS-reduce the 2 K partials.
__global__ __launch_bounds__(256, 4) void stage2_mfma(
    const float* __restrict__ ta, const float* __restrict__ tb,
    const float* __restrict__ Wout, float* __restrict__ out)
{
  constexpr int HC = 128, LDp = 132;
  const int b  = blockIdx.z;
  const int s0 = blockIdx.y * 16, t0 = blockIdx.x * 16;

  __shared__ float sa[16][LDp];
  __shared__ float sb[16][LDp];
  __shared__ f32x4 red[4][4][64];

  const int tid = threadIdx.x, wave = tid >> 6, lane = tid & 63;
  const int lg = lane >> 4;       // k sub-group (0..3)
  const int ln = lane & 15;       // A-row t / B-col r
  const int kh = wave & 1;        // K half
  const int sh = wave >> 1;       // s half
  const int kb = kh * 64;

  f32x4 acc[8] = {};

  const float* taB = ta + ((size_t)b * SQ + s0) * HD;
  const float* tbB = tb + ((size_t)b * SQ + t0) * HD;

  for (int c = 0; c < HD / HC; ++c) {
    __syncthreads();
    #pragma unroll
    for (int j = 0; j < 2; ++j) {
      int idx = tid + 256 * j, r = idx >> 5, q = idx & 31;
      *(float4*)&sa[r][q * 4] = *(const float4*)(taB + (size_t)r * HD + c * HC + q * 4);
      *(float4*)&sb[r][q * 4] = *(const float4*)(tbB + (size_t)r * HD + c * HC + q * 4);
    }
    __syncthreads();

    #pragma unroll
    for (int m = 0; m < 2; ++m) {
      const int kk = kb + m * 32 + lg * 8;   // k offset within chunk
      // B fragment: B[k][n] = Wout[n][c*HC+kk+j], zero rows n>=7
      bf16x8 bfr;
      float4 u = {0.f,0.f,0.f,0.f}, v = {0.f,0.f,0.f,0.f};
      if (ln < RR) {
        const float* wp = Wout + (size_t)ln * HD + c * HC + kk;
        u = *(const float4*)wp; v = *(const float4*)(wp + 4);
      }
      bfr[0]=f2bf(u.x); bfr[1]=f2bf(u.y); bfr[2]=f2bf(u.z); bfr[3]=f2bf(u.w);
      bfr[4]=f2bf(v.x); bfr[5]=f2bf(v.y); bfr[6]=f2bf(v.z); bfr[7]=f2bf(v.w);
      // tb values for this wave's t row (t = ln)
      float4 q0 = *(const float4*)&sb[ln][kk];
      float4 q1 = *(const float4*)&sb[ln][kk + 4];
      float bvv[8] = {q0.x,q0.y,q0.z,q0.w,q1.x,q1.y,q1.z,q1.w};

      #pragma unroll
      for (int si = 0; si < 8; ++si) {
        const float* ap = &sa[sh * 8 + si][kk];   // broadcast across 16-lane group
        float4 a0 = *(const float4*)ap;
        float4 a1 = *(const float4*)(ap + 4);
        float av[8] = {a0.x,a0.y,a0.z,a0.w,a1.x,a1.y,a1.z,a1.w};
        bf16x8 pa;
        #pragma unroll
        for (int j = 0; j < 8; ++j)
          pa[j] = f2bf(pair_tanh(av[j], bvv[j]));
        acc[si] = __builtin_amdgcn_mfma_f32_16x16x32_bf16(pa, bfr, acc[si], 0, 0, 0);
      }
    }
  }

  // reduce K halves across waves; wave w finalizes s = shf*8 + sg*4 + w
  #pragma unroll
  for (int sg = 0; sg < 2; ++sg) {
    __syncthreads();
    #pragma unroll
    for (int i = 0; i < 4; ++i)
      red[wave][i][lane] = acc[sg * 4 + i];
    __syncthreads();
    #pragma unroll
    for (int shf = 0; shf < 2; ++shf) {
      f32x4 sum = red[shf * 2 + 0][wave][lane] + red[shf * 2 + 1][wave][lane];
      if (ln < RR) {
        int s = s0 + shf * 8 + sg * 4 + wave;
        // C layout: row(M=t) = lg*4+reg, col(N=r) = ln
        float* op = out + (((size_t)b * SQ + s) * SQ + t0 + lg * 4) * RR + ln;
        op[0] = sum[0]; op[RR] = sum[1]; op[2 * RR] = sum[2]; op[3 * RR] = sum[3];
      }
    }
  }
}

extern "C" void kernel_launch(void* const* d_in, const int* in_sizes, int n_in,
                              void* d_out, int out_size, void* d_ws, size_t ws_size,
                              hipStream_t stream) {
  (void)in_sizes; (void)n_in; (void)out_size;
  const float* X    = (const float*)d_in[0];
  const float* Wsrc = (const float*)d_in[1];
  const float* bsrc = (const float*)d_in[2];
  const float* Wtgt = (const float*)d_in[3];
  const float* btgt = (const float*)d_in[4];
  const float* Wout = (const float*)d_in[5];
  float* out = (float*)d_out;

  float* taF = (float*)d_ws;                       // [1024,768] f32
  float* tbF = taF + (size_t)NB * SQ * HD;         // [1024,768] f32
  const size_t base = (size_t)2 * NB * SQ * HD * sizeof(float);
  const size_t need = base + ((size_t)NB * SQ * HD + 2 * (size_t)HD * HD) * sizeof(short);

  if (ws_size >= need) {
    short* Xb  = (short*)((char*)d_ws + base);
    short* Wsb = Xb + (size_t)NB * SQ * HD;
    short* Wtb = Wsb + (size_t)HD * HD;
    cvt_kernel<<<960, 256, 0, stream>>>(X, Wsrc, Wtgt, Xb, Wsb, Wtb);
    stage1_lds<<<dim3(16, 12, 2), 256, 0, stream>>>(Xb, Wsb, bsrc, Wtb, btgt, taF, tbF);
  } else {
    stage1_mfma<<<dim3(16, 12, 2), 256, 0, stream>>>(X, Wsrc, bsrc, Wtgt, btgt, taF, tbF);
  }
  stage2_mfma<<<dim3(SQ / 16, SQ / 16, NB), 256, 0, stream>>>(taF, tbF, Wout, out);
}